// Round 13
// baseline (541.764 us; speedup 1.0000x reference)
//
#include <hip/hip_runtime.h>
#include <hip/hip_bf16.h>
#include <math.h>

#define NS (16*256*64)   // 262144 samples
#define NCHUNK (NS/64)   // 4096
#define GRIDN 448        // <= 512 co-resident capacity (2 blocks/CU @ launch_bounds(512,4))
#define NTHR 512
#define PARTN (GRIDN*2)  // 896 partial slots (2 sub-blocks per block)
#define D 32
#define K 8

typedef __attribute__((ext_vector_type(8))) short bf16x8;
typedef __attribute__((ext_vector_type(8))) float f32x8;
typedef __attribute__((ext_vector_type(8))) __bf16 bf16v8;
typedef __attribute__((ext_vector_type(16))) float f32x16;

// ws float layout (memset zeroes [0, 9216) each call)
#define WS_ENERGY   0
#define WS_COVDIAG  1
#define WS_DONE     2
#define WS_BAR0     3
#define WS_BAR1     4
#define WS_BAR2     5
#define WS_C        16
#define WS_COEF     24
#define WS_SG       32
#define WS_S1       64
#define WS_S2       1024
#define WS_FRAGA    9216   // NOT zeroed (P writes all used entries)
#define WS_FRAGB    13312  // rows>=8 garbage-safe (unused MFMA output rows)
#define WS_PART     16384
#define PART_STRIDE 8456

__device__ __forceinline__ bf16x8 cvt8(f32x8 v) {
    union { bf16v8 h; bf16x8 s; } u;
    u.h = __builtin_convertvector(v, bf16v8);
    return u.s;
}
__device__ __forceinline__ unsigned short f2bf1(float f) {
    union { __bf16 h; unsigned short s; } u;
    u.h = (__bf16)f;
    return u.s;
}
__device__ __forceinline__ float bf2f(unsigned short u) {
    union { unsigned u32; float f; } v;
    v.u32 = ((unsigned)u) << 16;
    return v.f;
}
__device__ __forceinline__ float rdlane(float v, int lane) {
    return __uint_as_float(__builtin_amdgcn_readlane(__float_as_uint(v), lane));
}
__device__ __forceinline__ int dest_of(int e) {
    return (e < 8192) ? (WS_S2 + e)
         : (e < 8448) ? (WS_S1 + (e - 8192))
                      : (WS_SG + (e - 8448));
}
// grid barrier: per-thread release fence, block-collect, single arrival+spin, re-sync.
// Counters zeroed by the leading hipMemsetAsync each call. All GRIDN blocks are
// co-resident by occupancy construction, so spinning cannot deadlock.
__device__ __forceinline__ void gbar(float* ws, int slot) {
    __threadfence();
    __syncthreads();
    if (threadIdx.x == 0) {
        unsigned* ctr = (unsigned*)ws + slot;
        atomicAdd(ctr, 1u);
        while (__hip_atomic_load(ctr, __ATOMIC_RELAXED, __HIP_MEMORY_SCOPE_AGENT) < (unsigned)GRIDN) {
            __builtin_amdgcn_s_sleep(8);
        }
    }
    __syncthreads();
    __threadfence();
}

__global__ __launch_bounds__(512, 4) void k_fused(const float* __restrict__ z,
                                                  const float* __restrict__ g,
                                                  float* __restrict__ ws,
                                                  float* __restrict__ out) {
    __shared__ __align__(16) unsigned short zbt[2][32][72];  // bf16 z^T per sub-block
    __shared__ __align__(16) unsigned short gbt[2][8][72];   // bf16 gamma^T per sub-block
    __shared__ float Am[32][33];
    __shared__ float mus[32];
    __shared__ float bLs[32];
    __shared__ float redw[8];

    const int t   = threadIdx.x;
    const int bid = blockIdx.x;
    const int w   = t >> 6;        // 0..7
    const int l   = t & 63;
    const int col = l & 31;
    const int nh  = l >> 5;
    const int sub = w >> 2;        // 0/1: two 256-thread sub-blocks
    const int wl  = w & 3;
    const int k0  = 2 * wl;
    const int tl  = t & 255;       // thread within sub
    const int sz  = tl >> 2;       // staged sample
    const int dq  = (tl & 3) * 8;  // staged dim octet

    // ================= PHASE M: moments (R12 body, scalar S1, staging-reg SG) ==========
    {
        f32x16 acc0 = {}, acc1 = {};
        float s1a = 0.f, s1b = 0.f;
        float sg8[8];
#pragma unroll
        for (int k = 0; k < 8; k++) sg8[k] = 0.0f;

        int c = bid * 2 + sub;
        float4 za, zb4, ga4, gb4;
        {
            const float* zp = z + ((size_t)(c * 64 + sz)) * 32 + dq;
            za  = *(const float4*)zp;
            zb4 = *(const float4*)(zp + 4);
            if (tl < 64) {
                const float* gp = g + ((size_t)(c * 64 + tl)) * 8;
                ga4 = *(const float4*)gp;
                gb4 = *(const float4*)(gp + 4);
            }
        }
        for (; c < NCHUNK; c += PARTN) {
            __syncthreads();
            {
                float zf8[8] = {za.x, za.y, za.z, za.w, zb4.x, zb4.y, zb4.z, zb4.w};
#pragma unroll
                for (int i = 0; i < 8; i++) {
                    int d = dq + i;
                    zbt[sub][d][sz ^ (((d >> 3) & 3) << 3)] = f2bf1(zf8[i]);
                }
                if (tl < 64) {
                    float gf8[8] = {ga4.x, ga4.y, ga4.z, ga4.w, gb4.x, gb4.y, gb4.z, gb4.w};
#pragma unroll
                    for (int k = 0; k < 8; k++) {
                        gbt[sub][k][tl] = f2bf1(gf8[k]);
                        sg8[k] += gf8[k];            // exact f32 SG
                    }
                }
            }
            {
                int cn = c + PARTN;
                if (cn < NCHUNK) {
                    const float* zp = z + ((size_t)(cn * 64 + sz)) * 32 + dq;
                    za  = *(const float4*)zp;
                    zb4 = *(const float4*)(zp + 4);
                    if (tl < 64) {
                        const float* gp = g + ((size_t)(cn * 64 + tl)) * 8;
                        ga4 = *(const float4*)gp;
                        gb4 = *(const float4*)(gp + 4);
                    }
                }
            }
            __syncthreads();
            const int xs = ((col >> 3) & 3) << 3;
#pragma unroll
            for (int sc = 0; sc < 4; sc++) {
                const int s0 = sc * 16 + nh * 8;
                bf16x8 af = *(const bf16x8*)&zbt[sub][col][s0 ^ xs];
                bf16x8 g0 = *(const bf16x8*)&gbt[sub][k0][s0];
                bf16x8 g1 = *(const bf16x8*)&gbt[sub][k0 + 1][s0];
                f32x8 p0, p1;
#pragma unroll
                for (int j = 0; j < 8; j++) {
                    float zf = bf2f((unsigned short)af[j]);
                    p0[j] = bf2f((unsigned short)g0[j]) * zf;
                    p1[j] = bf2f((unsigned short)g1[j]) * zf;
                    s1a += p0[j];  s1b += p1[j];
                }
                acc0 = __builtin_amdgcn_mfma_f32_32x32x16_bf16(af, cvt8(p0), acc0, 0, 0, 0);
                acc1 = __builtin_amdgcn_mfma_f32_32x32x16_bf16(af, cvt8(p1), acc1, 0, 0, 0);
            }
        }
        s1a += __shfl_xor(s1a, 32);  s1b += __shfl_xor(s1b, 32);

        float* pb = ws + WS_PART + (size_t)(bid * 2 + sub) * PART_STRIDE;
#pragma unroll
        for (int r = 0; r < 16; r++) {
            int row = (r & 3) + 8 * (r >> 2) + 4 * nh;   // HW-verified C/D map (m74/m101)
            pb[(size_t)k0 * 1024 + row * 32 + col]       = acc0[r];
            pb[(size_t)(k0 + 1) * 1024 + row * 32 + col] = acc1[r];
        }
        if (l < 32) {
            pb[8192 + k0 * 32 + col]       = s1a;
            pb[8192 + (k0 + 1) * 32 + col] = s1b;
        }
        // SG: staged threads (tl<64 = one full wave per sub) hold partials
#pragma unroll
        for (int k = 0; k < 8; k++) {
            float v = sg8[k];
#pragma unroll
            for (int m = 1; m < 64; m <<= 1) v += __shfl_xor(v, m);
            if (tl == 0) pb[8448 + k] = v;
        }
    }
    gbar(ws, WS_BAR0);

    // ================= PHASE R: reduce partials (atomics into memset-zeroed sums) ======
    {
        unsigned u = (unsigned)bid * NTHR + t;
        if (u < 16u * 8456u) {
            int bg = (int)(u / 8456u);
            int e  = (int)(u - (unsigned)bg * 8456u);
            const float* pcol = ws + WS_PART + e;
            float s = 0.0f;
            const int b0 = bg * (PARTN / 16);
#pragma unroll 8
            for (int b = b0; b < b0 + PARTN / 16; b++) s += pcol[(size_t)b * PART_STRIDE];
            atomicAdd(&ws[dest_of(e)], s);
        }
    }
    gbar(ws, WS_BAR1);

    // ================= PHASE P: prep on blocks 0..7 (readlane Gauss-Jordan) ============
    if (bid < 8) {
        const int k   = bid;
        const bool act = (t < 64);
        const int c32 = t & 31;
        const bool right = act && (t >= 32);

        float sgk = 1.0f;
        if (act) sgk = ws[WS_SG + k];
        if (t < 32) mus[t] = ws[WS_S1 + k * 32 + t] / sgk;
        __syncthreads();

        float x[32];
        float logdet = 0.0f;
        if (act) {
            const float mc  = mus[c32];
            const float rsg = 1.0f / sgk;
            float dval = 1.0f;
#pragma unroll
            for (int r = 0; r < 32; r++) {
                float v;
                if (right) {
                    v = (r == c32) ? 1.0f : 0.0f;
                } else {
                    v = ws[WS_S2 + k * 1024 + r * 32 + c32] * rsg - mus[r] * mc;
                    if (r == c32) { v += 1.0e-6f + 1.0e-9f; dval = v; }
                }
                x[r] = v;
            }
            {
                float tdi = right ? 0.0f : 1.0f / dval;
#pragma unroll
                for (int m = 1; m < 64; m <<= 1) tdi += __shfl_xor(tdi, m);
                if (t == 0) atomicAdd(&ws[WS_COVDIAG], tdi);
            }
#pragma unroll
            for (int j = 0; j < 32; j++) {
                float piv = rdlane(x[j], j);
                float rp  = 1.0f / piv;
                logdet += __logf(piv);
                x[j] *= rp;
#pragma unroll
                for (int r = 0; r < 32; r++) {
                    if (r == j) continue;
                    float m = rdlane(x[r], j);
                    x[r] -= m * x[j];
                }
            }
            if (right) {
#pragma unroll
                for (int r = 0; r < 32; r++) Am[r][c32] = x[r];
            }
        }
        __syncthreads();

        if (t == 0) {
            float phi = sgk / (float)NS;
            ws[WS_COEF + k] = phi * __expf(-(8.0f * 1.8378770664093453f + 0.25f * logdet));
        }
        if (t < 32) {
            float s = 0.0f;
#pragma unroll
            for (int c = 0; c < 32; c++) s += Am[t][c] * mus[c];
            bLs[t] = s;
        }
        __syncthreads();
        if (act) {
            float cm = (t < 32) ? mus[c32] * bLs[c32] : 0.0f;
#pragma unroll
            for (int m = 1; m < 64; m <<= 1) cm += __shfl_xor(cm, m);
            if (t == 0) ws[WS_C + k] = cm;
            const int ph = t >> 5;
#pragma unroll
            for (int h = 0; h < 2; h++) {
                int cb = ph * 8 + 16 * h;
                unsigned uu[4];
#pragma unroll
                for (int q = 0; q < 4; q++) {
                    unsigned lo2 = f2bf1(Am[c32][cb + 2 * q]);
                    unsigned hi2 = f2bf1(Am[c32][cb + 2 * q + 1]);
                    uu[q] = lo2 | (hi2 << 16);
                }
                ((uint4*)(ws + WS_FRAGA))[(k * 2 + h) * 64 + t] = make_uint4(uu[0], uu[1], uu[2], uu[3]);
            }
            if (c32 == k) {
#pragma unroll
                for (int h = 0; h < 2; h++) {
                    int cb = ph * 8 + 16 * h;
                    unsigned uu[4];
#pragma unroll
                    for (int q = 0; q < 4; q++) {
                        unsigned lo2 = f2bf1(bLs[cb + 2 * q]);
                        unsigned hi2 = f2bf1(bLs[cb + 2 * q + 1]);
                        uu[q] = lo2 | (hi2 << 16);
                    }
                    ((uint4*)(ws + WS_FRAGB))[h * 64 + t] = make_uint4(uu[0], uu[1], uu[2], uu[3]);
                }
            }
        }
    }
    gbar(ws, WS_BAR2);

    // ================= PHASE E: energy (R12 body, grid-strided chunks) =================
    {
        const uint4* fragA = (const uint4*)(ws + WS_FRAGA);
        const uint4* fragB = (const uint4*)(ws + WS_FRAGB);
        float cf[8], cc[8];
#pragma unroll
        for (int k = 0; k < 8; k++) { cf[k] = ws[WS_COEF + k]; cc[k] = ws[WS_C + k]; }
        uint4 fbu0 = fragB[l];
        uint4 fbu1 = fragB[64 + l];

        float En = 0.0f;
        for (int ch0 = (bid * 8 + w) * 2; ch0 < NS / 32; ch0 += GRIDN * 16) {
#pragma unroll
            for (int ci = 0; ci < 2; ci++) {
                const int chunk = ch0 + ci;
                const int n0 = chunk * 32;
                const float* zb = z + (size_t)(n0 + col) * 32 + nh * 8;
                float4 a0 = *(const float4*)(zb + 0);
                float4 a1 = *(const float4*)(zb + 4);
                float4 a2 = *(const float4*)(zb + 16);
                float4 a3 = *(const float4*)(zb + 20);
                f32x8 zlo = {a0.x,a0.y,a0.z,a0.w,a1.x,a1.y,a1.z,a1.w};
                f32x8 zhi = {a2.x,a2.y,a2.z,a2.w,a3.x,a3.y,a3.z,a3.w};
                bf16x8 b0 = cvt8(zlo), b1 = cvt8(zhi);
                float olo[4], ohi[4];
#pragma unroll
                for (int j = 0; j < 4; j++) {
                    float mlo = nh ? zlo[j] : zlo[j + 4];
                    float mhi = nh ? zhi[j] : zhi[j + 4];
                    olo[j] = __shfl_xor(mlo, 32);
                    ohi[j] = __shfl_xor(mhi, 32);
                }
                float zdot[16];
#pragma unroll
                for (int j = 0; j < 4; j++) {
                    zdot[j]      = nh ? olo[j]     : zlo[j];
                    zdot[4 + j]  = nh ? zlo[4 + j] : olo[j];
                    zdot[8 + j]  = nh ? ohi[j]     : zhi[j];
                    zdot[12 + j] = nh ? zhi[4 + j] : ohi[j];
                }
                f32x16 acc2 = {};
                acc2 = __builtin_amdgcn_mfma_f32_32x32x16_bf16(*(const bf16x8*)&fbu0, b0, acc2, 0, 0, 0);
                acc2 = __builtin_amdgcn_mfma_f32_32x32x16_bf16(*(const bf16x8*)&fbu1, b1, acc2, 0, 0, 0);
                float oth[4];
#pragma unroll
                for (int r = 0; r < 4; r++) oth[r] = __shfl_xor(acc2[r], 32);
                float pk[8];
#pragma unroll
                for (int k = 0; k < 8; k++) {
                    uint4 fa0u = fragA[(k * 2 + 0) * 64 + l];
                    uint4 fa1u = fragA[(k * 2 + 1) * 64 + l];
                    f32x16 acc = {};
                    acc = __builtin_amdgcn_mfma_f32_32x32x16_bf16(*(const bf16x8*)&fa0u, b0, acc, 0, 0, 0);
                    acc = __builtin_amdgcn_mfma_f32_32x32x16_bf16(*(const bf16x8*)&fa1u, b1, acc, 0, 0, 0);
                    float p = 0.0f;
#pragma unroll
                    for (int r = 0; r < 16; r++) p += acc[r] * zdot[r];
                    p += __shfl_xor(p, 32);
                    pk[k] = p;
                }
                float ssum = 0.0f;
#pragma unroll
                for (int k = 0; k < 8; k++) {
                    float d2 = (k < 4) ? (nh ? oth[k] : acc2[k]) : (nh ? acc2[k - 4] : oth[k - 4]);
                    float E = pk[k] - 2.0f * d2 + cc[k];
                    ssum += cf[k] * __expf(-0.5f * E);
                }
                En += -__logf(ssum + 1.0e-6f);
            }
        }
#pragma unroll
        for (int m = 1; m < 64; m <<= 1) En += __shfl_xor(En, m);
        if (l == 0) redw[w] = En;
        __syncthreads();
        if (t == 0) {
            float s = 0.0f;
#pragma unroll
            for (int i = 0; i < 8; i++) s += redw[i];
            atomicAdd(&ws[WS_ENERGY], s);
            __threadfence();
            unsigned old = atomicAdd((unsigned*)ws + WS_DONE, 1u);
            if (old == GRIDN - 1) {   // last block finalizes out
                float se = atomicAdd(&ws[WS_ENERGY], 0.0f);
                se = se * 0.5f / (float)NS;   // each sample counted by 2 lane-halves
                if (!isfinite(se)) se = 0.0f;
                float cd = atomicAdd(&ws[WS_COVDIAG], 0.0f);
                if (!isfinite(cd)) cd = 0.0f;
                out[0] = 0.1f * se + 0.005f * cd;
            }
        }
    }
}

extern "C" void kernel_launch(void* const* d_in, const int* in_sizes, int n_in,
                              void* d_out, int out_size, void* d_ws, size_t ws_size,
                              hipStream_t stream) {
    const float* z = (const float*)d_in[0];
    const float* g = (const float*)d_in[1];
    float* out = (float*)d_out;
    float* ws  = (float*)d_ws;

    // zero ctrl + C + COEF + SG + S1 + S2 = floats [0, 9216): barriers/accumulators
    // deterministically reset every call (graph-legal async op).
    hipMemsetAsync(ws, 0, 9216 * sizeof(float), stream);
    k_fused<<<GRIDN, NTHR, 0, stream>>>(z, g, ws, out);
}

// Round 14
// 346.987 us; speedup vs baseline: 1.5613x; 1.5613x over previous
//
#include <hip/hip_runtime.h>
#include <hip/hip_bf16.h>
#include <math.h>

#define NS (16*256*64)   // 262144 samples
#define NCHUNK (NS/64)   // 4096
#define GRIDN 448        // <= 512 co-resident (2 blocks/CU @ launch_bounds(256,2))
#define NTHR 256
#define PARTN GRIDN
#define D 32
#define K 8

typedef __attribute__((ext_vector_type(8))) short bf16x8;
typedef __attribute__((ext_vector_type(8))) float f32x8;
typedef __attribute__((ext_vector_type(8))) __bf16 bf16v8;
typedef __attribute__((ext_vector_type(16))) float f32x16;

// ws float layout (memset zeroes [0, 9216) each call)
#define WS_ENERGY   0
#define WS_COVDIAG  1
#define WS_DONE     2
#define WS_BAR0     3
#define WS_BAR1     4
#define WS_BAR2     5
#define WS_C        16
#define WS_COEF     24
#define WS_SG       32
#define WS_S1       64
#define WS_S2       1024
#define WS_FRAGA    9216   // not zeroed: P writes all entries read by E
#define WS_FRAGB    13312  // unwritten lanes feed only unused MFMA output rows (safe)
#define WS_PART     16384
#define PART_STRIDE 8456

__device__ __forceinline__ bf16x8 cvt8(f32x8 v) {
    union { bf16v8 h; bf16x8 s; } u;
    u.h = __builtin_convertvector(v, bf16v8);
    return u.s;
}
__device__ __forceinline__ unsigned short f2bf1(float f) {
    union { __bf16 h; unsigned short s; } u;
    u.h = (__bf16)f;
    return u.s;
}
__device__ __forceinline__ float bf2f(unsigned short u) {
    union { unsigned u32; float f; } v;
    v.u32 = ((unsigned)u) << 16;
    return v.f;
}
__device__ __forceinline__ float rdlane(float v, int lane) {
    return __uint_as_float(__builtin_amdgcn_readlane(__float_as_uint(v), lane));
}
__device__ __forceinline__ int dest_of(int e) {
    return (e < 8192) ? (WS_S2 + e)
         : (e < 8448) ? (WS_S1 + (e - 8192))
                      : (WS_SG + (e - 8448));
}
// grid barrier (R13-validated): fence, block-collect, single arrival + spin, re-sync.
// All GRIDN blocks co-resident by occupancy construction -> no deadlock.
__device__ __forceinline__ void gbar(float* ws, int slot) {
    __threadfence();
    __syncthreads();
    if (threadIdx.x == 0) {
        unsigned* ctr = (unsigned*)ws + slot;
        atomicAdd(ctr, 1u);
        while (__hip_atomic_load(ctr, __ATOMIC_RELAXED, __HIP_MEMORY_SCOPE_AGENT) < (unsigned)GRIDN) {
            __builtin_amdgcn_s_sleep(8);
        }
    }
    __syncthreads();
    __threadfence();
}

__global__ __launch_bounds__(256, 2) void k_fused(const float* __restrict__ z,
                                                  const float* __restrict__ g,
                                                  float* __restrict__ ws,
                                                  float* __restrict__ out) {
    __shared__ __align__(16) unsigned short zbt[32][72];  // bf16 z^T, pad 72
    __shared__ __align__(16) unsigned short gbt[8][72];   // bf16 gamma^T
    __shared__ float Am[32][33];
    __shared__ float mus[32];
    __shared__ float bLs[32];
    __shared__ float redw[4];

    const int t   = threadIdx.x;
    const int bid = blockIdx.x;
    const int w   = t >> 6;        // 0..3
    const int l   = t & 63;
    const int col = l & 31;
    const int nh  = l >> 5;
    const int k0  = 2 * w;
    const int sz  = t >> 2;        // staged sample
    const int dq  = (t & 3) * 8;   // staged dim octet

    // ================= PHASE M: moments (R10/R13-proven body) =================
    {
        f32x16 acc0 = {}, acc1 = {};
        float s1a = 0.f, s1b = 0.f;
        float sg8[8];
#pragma unroll
        for (int k = 0; k < 8; k++) sg8[k] = 0.0f;

        int c = bid;
        float4 za, zb4, ga4, gb4;
        {
            const float* zp = z + ((size_t)(c * 64 + sz)) * 32 + dq;
            za  = *(const float4*)zp;
            zb4 = *(const float4*)(zp + 4);
            if (t < 64) {
                const float* gp = g + ((size_t)(c * 64 + t)) * 8;
                ga4 = *(const float4*)gp;
                gb4 = *(const float4*)(gp + 4);
            }
        }
        for (; c < NCHUNK; c += GRIDN) {
            __syncthreads();
            {
                float zf8[8] = {za.x, za.y, za.z, za.w, zb4.x, zb4.y, zb4.z, zb4.w};
#pragma unroll
                for (int i = 0; i < 8; i++) {
                    int d = dq + i;
                    zbt[d][sz ^ (((d >> 3) & 3) << 3)] = f2bf1(zf8[i]);
                }
                if (t < 64) {
                    float gf8[8] = {ga4.x, ga4.y, ga4.z, ga4.w, gb4.x, gb4.y, gb4.z, gb4.w};
#pragma unroll
                    for (int k = 0; k < 8; k++) {
                        gbt[k][t] = f2bf1(gf8[k]);
                        sg8[k] += gf8[k];            // exact f32 SG in staging-thread regs
                    }
                }
            }
            {
                int cn = c + GRIDN;
                if (cn < NCHUNK) {
                    const float* zp = z + ((size_t)(cn * 64 + sz)) * 32 + dq;
                    za  = *(const float4*)zp;
                    zb4 = *(const float4*)(zp + 4);
                    if (t < 64) {
                        const float* gp = g + ((size_t)(cn * 64 + t)) * 8;
                        ga4 = *(const float4*)gp;
                        gb4 = *(const float4*)(gp + 4);
                    }
                }
            }
            __syncthreads();
            const int xs = ((col >> 3) & 3) << 3;
#pragma unroll
            for (int sc = 0; sc < 4; sc++) {
                const int s0 = sc * 16 + nh * 8;
                bf16x8 af = *(const bf16x8*)&zbt[col][s0 ^ xs];
                bf16x8 g0 = *(const bf16x8*)&gbt[k0][s0];
                bf16x8 g1 = *(const bf16x8*)&gbt[k0 + 1][s0];
                f32x8 p0, p1;
#pragma unroll
                for (int j = 0; j < 8; j++) {
                    float zf = bf2f((unsigned short)af[j]);
                    p0[j] = bf2f((unsigned short)g0[j]) * zf;
                    p1[j] = bf2f((unsigned short)g1[j]) * zf;
                    s1a += p0[j];  s1b += p1[j];
                }
                acc0 = __builtin_amdgcn_mfma_f32_32x32x16_bf16(af, cvt8(p0), acc0, 0, 0, 0);
                acc1 = __builtin_amdgcn_mfma_f32_32x32x16_bf16(af, cvt8(p1), acc1, 0, 0, 0);
            }
        }
        s1a += __shfl_xor(s1a, 32);  s1b += __shfl_xor(s1b, 32);

        float* pb = ws + WS_PART + (size_t)bid * PART_STRIDE;
#pragma unroll
        for (int r = 0; r < 16; r++) {
            int row = (r & 3) + 8 * (r >> 2) + 4 * nh;   // HW-verified C/D map (m74/m101)
            pb[(size_t)k0 * 1024 + row * 32 + col]       = acc0[r];
            pb[(size_t)(k0 + 1) * 1024 + row * 32 + col] = acc1[r];
        }
        if (l < 32) {
            pb[8192 + k0 * 32 + col]       = s1a;
            pb[8192 + (k0 + 1) * 32 + col] = s1b;
        }
        if (t < 64) {   // SG: staging wave holds partials
#pragma unroll
            for (int k = 0; k < 8; k++) {
                float v = sg8[k];
#pragma unroll
                for (int m = 1; m < 64; m <<= 1) v += __shfl_xor(v, m);
                if (t == 0) pb[8448 + k] = v;
            }
        }
    }
    gbar(ws, WS_BAR0);

    // ================= PHASE R: reduce partials (atomics into memset-zeroed sums) ======
    {
#pragma unroll
        for (int pass = 0; pass < 2; pass++) {
            unsigned u = (unsigned)bid * NTHR + t + (unsigned)pass * (GRIDN * NTHR);
            if (u < 16u * 8456u) {
                int bg = (int)(u / 8456u);
                int e  = (int)(u - (unsigned)bg * 8456u);
                const float* pcol = ws + WS_PART + e;
                float s = 0.0f;
                const int b0 = bg * (PARTN / 16);   // 28 rows per group
#pragma unroll 7
                for (int b = b0; b < b0 + PARTN / 16; b++) s += pcol[(size_t)b * PART_STRIDE];
                atomicAdd(&ws[dest_of(e)], s);
            }
        }
    }
    gbar(ws, WS_BAR1);

    // ================= PHASE P: prep on blocks 0..7 (readlane Gauss-Jordan) ============
    if (bid < 8) {
        const int k   = bid;
        const bool act = (t < 64);
        const int c32 = t & 31;
        const bool right = act && (t >= 32);

        float sgk = 1.0f;
        if (act) sgk = ws[WS_SG + k];
        if (t < 32) mus[t] = ws[WS_S1 + k * 32 + t] / sgk;
        __syncthreads();

        float x[32];
        float logdet = 0.0f;
        if (act) {
            const float mc  = mus[c32];
            const float rsg = 1.0f / sgk;
            float dval = 1.0f;
#pragma unroll
            for (int r = 0; r < 32; r++) {
                float v;
                if (right) {
                    v = (r == c32) ? 1.0f : 0.0f;
                } else {
                    v = ws[WS_S2 + k * 1024 + r * 32 + c32] * rsg - mus[r] * mc;
                    if (r == c32) { v += 1.0e-6f + 1.0e-9f; dval = v; }
                }
                x[r] = v;
            }
            {
                float tdi = right ? 0.0f : 1.0f / dval;
#pragma unroll
                for (int m = 1; m < 64; m <<= 1) tdi += __shfl_xor(tdi, m);
                if (t == 0) atomicAdd(&ws[WS_COVDIAG], tdi);
            }
#pragma unroll
            for (int j = 0; j < 32; j++) {
                float piv = rdlane(x[j], j);
                float rp  = 1.0f / piv;
                logdet += __logf(piv);
                x[j] *= rp;
#pragma unroll
                for (int r = 0; r < 32; r++) {
                    if (r == j) continue;
                    float m = rdlane(x[r], j);
                    x[r] -= m * x[j];
                }
            }
            if (right) {
#pragma unroll
                for (int r = 0; r < 32; r++) Am[r][c32] = x[r];
            }
        }
        __syncthreads();

        if (t == 0) {
            float phi = sgk / (float)NS;
            ws[WS_COEF + k] = phi * __expf(-(8.0f * 1.8378770664093453f + 0.25f * logdet));
        }
        if (t < 32) {
            float s = 0.0f;
#pragma unroll
            for (int c = 0; c < 32; c++) s += Am[t][c] * mus[c];
            bLs[t] = s;
        }
        __syncthreads();
        if (act) {
            float cm = (t < 32) ? mus[c32] * bLs[c32] : 0.0f;
#pragma unroll
            for (int m = 1; m < 64; m <<= 1) cm += __shfl_xor(cm, m);
            if (t == 0) ws[WS_C + k] = cm;
            const int ph = t >> 5;
#pragma unroll
            for (int h = 0; h < 2; h++) {
                int cb = ph * 8 + 16 * h;
                unsigned uu[4];
#pragma unroll
                for (int q = 0; q < 4; q++) {
                    unsigned lo2 = f2bf1(Am[c32][cb + 2 * q]);
                    unsigned hi2 = f2bf1(Am[c32][cb + 2 * q + 1]);
                    uu[q] = lo2 | (hi2 << 16);
                }
                ((uint4*)(ws + WS_FRAGA))[(k * 2 + h) * 64 + t] = make_uint4(uu[0], uu[1], uu[2], uu[3]);
            }
            if (c32 == k) {
#pragma unroll
                for (int h = 0; h < 2; h++) {
                    int cb = ph * 8 + 16 * h;
                    unsigned uu[4];
#pragma unroll
                    for (int q = 0; q < 4; q++) {
                        unsigned lo2 = f2bf1(bLs[cb + 2 * q]);
                        unsigned hi2 = f2bf1(bLs[cb + 2 * q + 1]);
                        uu[q] = lo2 | (hi2 << 16);
                    }
                    ((uint4*)(ws + WS_FRAGB))[h * 64 + t] = make_uint4(uu[0], uu[1], uu[2], uu[3]);
                }
            }
        }
    }
    gbar(ws, WS_BAR2);

    // ================= PHASE E: energy (R12 body, grid-strided; finalize via done ctr) =
    {
        const uint4* fragA = (const uint4*)(ws + WS_FRAGA);
        const uint4* fragB = (const uint4*)(ws + WS_FRAGB);
        float cf[8], cc[8];
#pragma unroll
        for (int k = 0; k < 8; k++) { cf[k] = ws[WS_COEF + k]; cc[k] = ws[WS_C + k]; }
        uint4 fbu0 = fragB[l];
        uint4 fbu1 = fragB[64 + l];

        float En = 0.0f;
        for (int chunk = bid * 4 + w; chunk < NS / 32; chunk += GRIDN * 4) {
            const int n0 = chunk * 32;
            const float* zb = z + (size_t)(n0 + col) * 32 + nh * 8;
            float4 a0 = *(const float4*)(zb + 0);
            float4 a1 = *(const float4*)(zb + 4);
            float4 a2 = *(const float4*)(zb + 16);
            float4 a3 = *(const float4*)(zb + 20);
            f32x8 zlo = {a0.x,a0.y,a0.z,a0.w,a1.x,a1.y,a1.z,a1.w};
            f32x8 zhi = {a2.x,a2.y,a2.z,a2.w,a3.x,a3.y,a3.z,a3.w};
            bf16x8 b0 = cvt8(zlo), b1 = cvt8(zhi);
            float olo[4], ohi[4];
#pragma unroll
            for (int j = 0; j < 4; j++) {
                float mlo = nh ? zlo[j] : zlo[j + 4];
                float mhi = nh ? zhi[j] : zhi[j + 4];
                olo[j] = __shfl_xor(mlo, 32);
                ohi[j] = __shfl_xor(mhi, 32);
            }
            float zdot[16];
#pragma unroll
            for (int j = 0; j < 4; j++) {
                zdot[j]      = nh ? olo[j]     : zlo[j];
                zdot[4 + j]  = nh ? zlo[4 + j] : olo[j];
                zdot[8 + j]  = nh ? ohi[j]     : zhi[j];
                zdot[12 + j] = nh ? zhi[4 + j] : ohi[j];
            }
            f32x16 acc2 = {};
            acc2 = __builtin_amdgcn_mfma_f32_32x32x16_bf16(*(const bf16x8*)&fbu0, b0, acc2, 0, 0, 0);
            acc2 = __builtin_amdgcn_mfma_f32_32x32x16_bf16(*(const bf16x8*)&fbu1, b1, acc2, 0, 0, 0);
            float oth[4];
#pragma unroll
            for (int r = 0; r < 4; r++) oth[r] = __shfl_xor(acc2[r], 32);
            float pk[8];
#pragma unroll
            for (int k = 0; k < 8; k++) {
                uint4 fa0u = fragA[(k * 2 + 0) * 64 + l];
                uint4 fa1u = fragA[(k * 2 + 1) * 64 + l];
                f32x16 acc = {};
                acc = __builtin_amdgcn_mfma_f32_32x32x16_bf16(*(const bf16x8*)&fa0u, b0, acc, 0, 0, 0);
                acc = __builtin_amdgcn_mfma_f32_32x32x16_bf16(*(const bf16x8*)&fa1u, b1, acc, 0, 0, 0);
                float p = 0.0f;
#pragma unroll
                for (int r = 0; r < 16; r++) p += acc[r] * zdot[r];
                p += __shfl_xor(p, 32);
                pk[k] = p;
            }
            float ssum = 0.0f;
#pragma unroll
            for (int k = 0; k < 8; k++) {
                float d2 = (k < 4) ? (nh ? oth[k] : acc2[k]) : (nh ? acc2[k - 4] : oth[k - 4]);
                float E = pk[k] - 2.0f * d2 + cc[k];
                ssum += cf[k] * __expf(-0.5f * E);
            }
            En += -__logf(ssum + 1.0e-6f);
        }
#pragma unroll
        for (int m = 1; m < 64; m <<= 1) En += __shfl_xor(En, m);
        if (l == 0) redw[w] = En;
        __syncthreads();
        if (t == 0) {
            float s = redw[0] + redw[1] + redw[2] + redw[3];
            atomicAdd(&ws[WS_ENERGY], s);
            __threadfence();
            unsigned old = atomicAdd((unsigned*)ws + WS_DONE, 1u);
            if (old == GRIDN - 1) {   // last block finalizes out
                float se = atomicAdd(&ws[WS_ENERGY], 0.0f);
                se = se * 0.5f / (float)NS;   // each sample counted by 2 lane-halves
                if (!isfinite(se)) se = 0.0f;
                float cd = atomicAdd(&ws[WS_COVDIAG], 0.0f);
                if (!isfinite(cd)) cd = 0.0f;
                out[0] = 0.1f * se + 0.005f * cd;
            }
        }
    }
}

extern "C" void kernel_launch(void* const* d_in, const int* in_sizes, int n_in,
                              void* d_out, int out_size, void* d_ws, size_t ws_size,
                              hipStream_t stream) {
    const float* z = (const float*)d_in[0];
    const float* g = (const float*)d_in[1];
    float* out = (float*)d_out;
    float* ws  = (float*)d_ws;

    // zero barriers + accumulators + S1/S2/SG sums: floats [0, 9216), every call.
    hipMemsetAsync(ws, 0, 9216 * sizeof(float), stream);
    k_fused<<<GRIDN, NTHR, 0, stream>>>(z, g, ws, out);
}

// Round 15
// 336.954 us; speedup vs baseline: 1.6078x; 1.0298x over previous
//
#include <hip/hip_runtime.h>
#include <hip/hip_bf16.h>
#include <math.h>

#define NS (16*256*64)   // 262144 samples
#define NCHUNK (NS/64)   // 4096
#define GRIDN 448        // <= 512 co-resident (2 blocks/CU @ launch_bounds(256,2))
#define NTHR 256
#define PARTN GRIDN
#define D 32
#define K 8

typedef __attribute__((ext_vector_type(8))) short bf16x8;
typedef __attribute__((ext_vector_type(8))) float f32x8;
typedef __attribute__((ext_vector_type(8))) __bf16 bf16v8;
typedef __attribute__((ext_vector_type(16))) float f32x16;

// ws float layout (memset zeroes [0, 9216) each call)
#define WS_ENERGY   0
#define WS_COVDIAG  1
#define WS_DONE     2
#define WS_BAR0     3
#define WS_BAR1     4
#define WS_BAR2     5
#define WS_C        16
#define WS_COEF     24
#define WS_SG       32
#define WS_S1       64
#define WS_S2       1024
#define WS_FRAGA    9216   // not zeroed: P writes all entries read by E
#define WS_FRAGB    13312  // unwritten lanes feed only unused MFMA output rows (safe)
#define WS_PART     16384
#define PART_STRIDE 8456

__device__ __forceinline__ bf16x8 cvt8(f32x8 v) {
    union { bf16v8 h; bf16x8 s; } u;
    u.h = __builtin_convertvector(v, bf16v8);
    return u.s;
}
__device__ __forceinline__ unsigned short f2bf1(float f) {
    union { __bf16 h; unsigned short s; } u;
    u.h = (__bf16)f;
    return u.s;
}
__device__ __forceinline__ float bf2f(unsigned short u) {
    union { unsigned u32; float f; } v;
    v.u32 = ((unsigned)u) << 16;
    return v.f;
}
__device__ __forceinline__ float rdlane(float v, int lane) {
    return __uint_as_float(__builtin_amdgcn_readlane(__float_as_uint(v), lane));
}
__device__ __forceinline__ int dest_of(int e) {
    return (e < 8192) ? (WS_S2 + e)
         : (e < 8448) ? (WS_S1 + (e - 8192))
                      : (WS_SG + (e - 8448));
}
// Grid barrier. R14 lesson: plain atomic LOAD polls can be served by the
// spinner's own (non-cross-coherent) XCD L2 -> stale counter -> ~100us/barrier.
// Fix: poll with an RMW (atomicAdd(ctr,0)) which is ALWAYS serviced at the
// device-coherent point (m20 semantics). s_sleep(16) backoff bounds contention.
__device__ __forceinline__ void gbar(float* ws, int slot) {
    __threadfence();
    __syncthreads();
    if (threadIdx.x == 0) {
        unsigned* ctr = (unsigned*)ws + slot;
        unsigned v = atomicAdd(ctr, 1u) + 1u;
        while (v < (unsigned)GRIDN) {
            __builtin_amdgcn_s_sleep(16);
            v = atomicAdd(ctr, 0u);   // coherent RMW poll
        }
    }
    __syncthreads();
    __threadfence();
}

__global__ __launch_bounds__(256, 2) void k_fused(const float* __restrict__ z,
                                                  const float* __restrict__ g,
                                                  float* __restrict__ ws,
                                                  float* __restrict__ out) {
    __shared__ __align__(16) unsigned short zbt[32][72];  // bf16 z^T, pad 72
    __shared__ __align__(16) unsigned short gbt[8][72];   // bf16 gamma^T
    __shared__ float Am[32][33];
    __shared__ float mus[32];
    __shared__ float bLs[32];
    __shared__ float redw[4];

    const int t   = threadIdx.x;
    const int bid = blockIdx.x;
    const int w   = t >> 6;        // 0..3
    const int l   = t & 63;
    const int col = l & 31;
    const int nh  = l >> 5;
    const int k0  = 2 * w;
    const int sz  = t >> 2;        // staged sample
    const int dq  = (t & 3) * 8;   // staged dim octet

    // ================= PHASE M: moments (R10/R14-proven body) =================
    {
        f32x16 acc0 = {}, acc1 = {};
        float s1a = 0.f, s1b = 0.f;
        float sg8[8];
#pragma unroll
        for (int k = 0; k < 8; k++) sg8[k] = 0.0f;

        int c = bid;
        float4 za, zb4, ga4, gb4;
        {
            const float* zp = z + ((size_t)(c * 64 + sz)) * 32 + dq;
            za  = *(const float4*)zp;
            zb4 = *(const float4*)(zp + 4);
            if (t < 64) {
                const float* gp = g + ((size_t)(c * 64 + t)) * 8;
                ga4 = *(const float4*)gp;
                gb4 = *(const float4*)(gp + 4);
            }
        }
        for (; c < NCHUNK; c += GRIDN) {
            __syncthreads();
            {
                float zf8[8] = {za.x, za.y, za.z, za.w, zb4.x, zb4.y, zb4.z, zb4.w};
#pragma unroll
                for (int i = 0; i < 8; i++) {
                    int d = dq + i;
                    zbt[d][sz ^ (((d >> 3) & 3) << 3)] = f2bf1(zf8[i]);
                }
                if (t < 64) {
                    float gf8[8] = {ga4.x, ga4.y, ga4.z, ga4.w, gb4.x, gb4.y, gb4.z, gb4.w};
#pragma unroll
                    for (int k = 0; k < 8; k++) {
                        gbt[k][t] = f2bf1(gf8[k]);
                        sg8[k] += gf8[k];            // exact f32 SG in staging-thread regs
                    }
                }
            }
            {
                int cn = c + GRIDN;
                if (cn < NCHUNK) {
                    const float* zp = z + ((size_t)(cn * 64 + sz)) * 32 + dq;
                    za  = *(const float4*)zp;
                    zb4 = *(const float4*)(zp + 4);
                    if (t < 64) {
                        const float* gp = g + ((size_t)(cn * 64 + t)) * 8;
                        ga4 = *(const float4*)gp;
                        gb4 = *(const float4*)(gp + 4);
                    }
                }
            }
            __syncthreads();
            const int xs = ((col >> 3) & 3) << 3;
#pragma unroll
            for (int sc = 0; sc < 4; sc++) {
                const int s0 = sc * 16 + nh * 8;
                bf16x8 af = *(const bf16x8*)&zbt[col][s0 ^ xs];
                bf16x8 g0 = *(const bf16x8*)&gbt[k0][s0];
                bf16x8 g1 = *(const bf16x8*)&gbt[k0 + 1][s0];
                f32x8 p0, p1;
#pragma unroll
                for (int j = 0; j < 8; j++) {
                    float zf = bf2f((unsigned short)af[j]);
                    p0[j] = bf2f((unsigned short)g0[j]) * zf;
                    p1[j] = bf2f((unsigned short)g1[j]) * zf;
                    s1a += p0[j];  s1b += p1[j];
                }
                acc0 = __builtin_amdgcn_mfma_f32_32x32x16_bf16(af, cvt8(p0), acc0, 0, 0, 0);
                acc1 = __builtin_amdgcn_mfma_f32_32x32x16_bf16(af, cvt8(p1), acc1, 0, 0, 0);
            }
        }
        s1a += __shfl_xor(s1a, 32);  s1b += __shfl_xor(s1b, 32);

        float* pb = ws + WS_PART + (size_t)bid * PART_STRIDE;
#pragma unroll
        for (int r = 0; r < 16; r++) {
            int row = (r & 3) + 8 * (r >> 2) + 4 * nh;   // HW-verified C/D map (m74/m101)
            pb[(size_t)k0 * 1024 + row * 32 + col]       = acc0[r];
            pb[(size_t)(k0 + 1) * 1024 + row * 32 + col] = acc1[r];
        }
        if (l < 32) {
            pb[8192 + k0 * 32 + col]       = s1a;
            pb[8192 + (k0 + 1) * 32 + col] = s1b;
        }
        if (t < 64) {   // SG: staging wave holds partials
#pragma unroll
            for (int k = 0; k < 8; k++) {
                float v = sg8[k];
#pragma unroll
                for (int m = 1; m < 64; m <<= 1) v += __shfl_xor(v, m);
                if (t == 0) pb[8448 + k] = v;
            }
        }
    }
    gbar(ws, WS_BAR0);

    // ================= PHASE R: reduce partials (atomics into memset-zeroed sums) ======
    {
#pragma unroll
        for (int pass = 0; pass < 2; pass++) {
            unsigned u = (unsigned)bid * NTHR + t + (unsigned)pass * (GRIDN * NTHR);
            if (u < 16u * 8456u) {
                int bg = (int)(u / 8456u);
                int e  = (int)(u - (unsigned)bg * 8456u);
                const float* pcol = ws + WS_PART + e;
                float s = 0.0f;
                const int b0 = bg * (PARTN / 16);   // 28 rows per group
#pragma unroll 7
                for (int b = b0; b < b0 + PARTN / 16; b++) s += pcol[(size_t)b * PART_STRIDE];
                atomicAdd(&ws[dest_of(e)], s);
            }
        }
    }
    gbar(ws, WS_BAR1);

    // ================= PHASE P: prep on blocks 0..7 (readlane Gauss-Jordan) ============
    if (bid < 8) {
        const int k   = bid;
        const bool act = (t < 64);
        const int c32 = t & 31;
        const bool right = act && (t >= 32);

        float sgk = 1.0f;
        if (act) sgk = ws[WS_SG + k];
        if (t < 32) mus[t] = ws[WS_S1 + k * 32 + t] / sgk;
        __syncthreads();

        float x[32];
        float logdet = 0.0f;
        if (act) {
            const float mc  = mus[c32];
            const float rsg = 1.0f / sgk;
            float dval = 1.0f;
#pragma unroll
            for (int r = 0; r < 32; r++) {
                float v;
                if (right) {
                    v = (r == c32) ? 1.0f : 0.0f;
                } else {
                    v = ws[WS_S2 + k * 1024 + r * 32 + c32] * rsg - mus[r] * mc;
                    if (r == c32) { v += 1.0e-6f + 1.0e-9f; dval = v; }
                }
                x[r] = v;
            }
            {
                float tdi = right ? 0.0f : 1.0f / dval;
#pragma unroll
                for (int m = 1; m < 64; m <<= 1) tdi += __shfl_xor(tdi, m);
                if (t == 0) atomicAdd(&ws[WS_COVDIAG], tdi);
            }
#pragma unroll
            for (int j = 0; j < 32; j++) {
                float piv = rdlane(x[j], j);
                float rp  = 1.0f / piv;
                logdet += __logf(piv);
                x[j] *= rp;
#pragma unroll
                for (int r = 0; r < 32; r++) {
                    if (r == j) continue;
                    float m = rdlane(x[r], j);
                    x[r] -= m * x[j];
                }
            }
            if (right) {
#pragma unroll
                for (int r = 0; r < 32; r++) Am[r][c32] = x[r];
            }
        }
        __syncthreads();

        if (t == 0) {
            float phi = sgk / (float)NS;
            ws[WS_COEF + k] = phi * __expf(-(8.0f * 1.8378770664093453f + 0.25f * logdet));
        }
        if (t < 32) {
            float s = 0.0f;
#pragma unroll
            for (int c = 0; c < 32; c++) s += Am[t][c] * mus[c];
            bLs[t] = s;
        }
        __syncthreads();
        if (act) {
            float cm = (t < 32) ? mus[c32] * bLs[c32] : 0.0f;
#pragma unroll
            for (int m = 1; m < 64; m <<= 1) cm += __shfl_xor(cm, m);
            if (t == 0) ws[WS_C + k] = cm;
            const int ph = t >> 5;
#pragma unroll
            for (int h = 0; h < 2; h++) {
                int cb = ph * 8 + 16 * h;
                unsigned uu[4];
#pragma unroll
                for (int q = 0; q < 4; q++) {
                    unsigned lo2 = f2bf1(Am[c32][cb + 2 * q]);
                    unsigned hi2 = f2bf1(Am[c32][cb + 2 * q + 1]);
                    uu[q] = lo2 | (hi2 << 16);
                }
                ((uint4*)(ws + WS_FRAGA))[(k * 2 + h) * 64 + t] = make_uint4(uu[0], uu[1], uu[2], uu[3]);
            }
            if (c32 == k) {
#pragma unroll
                for (int h = 0; h < 2; h++) {
                    int cb = ph * 8 + 16 * h;
                    unsigned uu[4];
#pragma unroll
                    for (int q = 0; q < 4; q++) {
                        unsigned lo2 = f2bf1(bLs[cb + 2 * q]);
                        unsigned hi2 = f2bf1(bLs[cb + 2 * q + 1]);
                        uu[q] = lo2 | (hi2 << 16);
                    }
                    ((uint4*)(ws + WS_FRAGB))[h * 64 + t] = make_uint4(uu[0], uu[1], uu[2], uu[3]);
                }
            }
        }
    }
    gbar(ws, WS_BAR2);

    // ================= PHASE E: energy (R12 body, grid-strided; finalize via done ctr) =
    {
        const uint4* fragA = (const uint4*)(ws + WS_FRAGA);
        const uint4* fragB = (const uint4*)(ws + WS_FRAGB);
        float cf[8], cc[8];
#pragma unroll
        for (int k = 0; k < 8; k++) { cf[k] = ws[WS_COEF + k]; cc[k] = ws[WS_C + k]; }
        uint4 fbu0 = fragB[l];
        uint4 fbu1 = fragB[64 + l];

        float En = 0.0f;
        for (int chunk = bid * 4 + w; chunk < NS / 32; chunk += GRIDN * 4) {
            const int n0 = chunk * 32;
            const float* zb = z + (size_t)(n0 + col) * 32 + nh * 8;
            float4 a0 = *(const float4*)(zb + 0);
            float4 a1 = *(const float4*)(zb + 4);
            float4 a2 = *(const float4*)(zb + 16);
            float4 a3 = *(const float4*)(zb + 20);
            f32x8 zlo = {a0.x,a0.y,a0.z,a0.w,a1.x,a1.y,a1.z,a1.w};
            f32x8 zhi = {a2.x,a2.y,a2.z,a2.w,a3.x,a3.y,a3.z,a3.w};
            bf16x8 b0 = cvt8(zlo), b1 = cvt8(zhi);
            float olo[4], ohi[4];
#pragma unroll
            for (int j = 0; j < 4; j++) {
                float mlo = nh ? zlo[j] : zlo[j + 4];
                float mhi = nh ? zhi[j] : zhi[j + 4];
                olo[j] = __shfl_xor(mlo, 32);
                ohi[j] = __shfl_xor(mhi, 32);
            }
            float zdot[16];
#pragma unroll
            for (int j = 0; j < 4; j++) {
                zdot[j]      = nh ? olo[j]     : zlo[j];
                zdot[4 + j]  = nh ? zlo[4 + j] : olo[j];
                zdot[8 + j]  = nh ? ohi[j]     : zhi[j];
                zdot[12 + j] = nh ? zhi[4 + j] : ohi[j];
            }
            f32x16 acc2 = {};
            acc2 = __builtin_amdgcn_mfma_f32_32x32x16_bf16(*(const bf16x8*)&fbu0, b0, acc2, 0, 0, 0);
            acc2 = __builtin_amdgcn_mfma_f32_32x32x16_bf16(*(const bf16x8*)&fbu1, b1, acc2, 0, 0, 0);
            float oth[4];
#pragma unroll
            for (int r = 0; r < 4; r++) oth[r] = __shfl_xor(acc2[r], 32);
            float pk[8];
#pragma unroll
            for (int k = 0; k < 8; k++) {
                uint4 fa0u = fragA[(k * 2 + 0) * 64 + l];
                uint4 fa1u = fragA[(k * 2 + 1) * 64 + l];
                f32x16 acc = {};
                acc = __builtin_amdgcn_mfma_f32_32x32x16_bf16(*(const bf16x8*)&fa0u, b0, acc, 0, 0, 0);
                acc = __builtin_amdgcn_mfma_f32_32x32x16_bf16(*(const bf16x8*)&fa1u, b1, acc, 0, 0, 0);
                float p = 0.0f;
#pragma unroll
                for (int r = 0; r < 16; r++) p += acc[r] * zdot[r];
                p += __shfl_xor(p, 32);
                pk[k] = p;
            }
            float ssum = 0.0f;
#pragma unroll
            for (int k = 0; k < 8; k++) {
                float d2 = (k < 4) ? (nh ? oth[k] : acc2[k]) : (nh ? acc2[k - 4] : oth[k - 4]);
                float E = pk[k] - 2.0f * d2 + cc[k];
                ssum += cf[k] * __expf(-0.5f * E);
            }
            En += -__logf(ssum + 1.0e-6f);
        }
#pragma unroll
        for (int m = 1; m < 64; m <<= 1) En += __shfl_xor(En, m);
        if (l == 0) redw[w] = En;
        __syncthreads();
        if (t == 0) {
            float s = redw[0] + redw[1] + redw[2] + redw[3];
            atomicAdd(&ws[WS_ENERGY], s);
            __threadfence();
            unsigned old = atomicAdd((unsigned*)ws + WS_DONE, 1u);
            if (old == GRIDN - 1) {   // last block finalizes out
                float se = atomicAdd(&ws[WS_ENERGY], 0.0f);
                se = se * 0.5f / (float)NS;   // each sample counted by 2 lane-halves
                if (!isfinite(se)) se = 0.0f;
                float cd = atomicAdd(&ws[WS_COVDIAG], 0.0f);
                if (!isfinite(cd)) cd = 0.0f;
                out[0] = 0.1f * se + 0.005f * cd;
            }
        }
    }
}

extern "C" void kernel_launch(void* const* d_in, const int* in_sizes, int n_in,
                              void* d_out, int out_size, void* d_ws, size_t ws_size,
                              hipStream_t stream) {
    const float* z = (const float*)d_in[0];
    const float* g = (const float*)d_in[1];
    float* out = (float*)d_out;
    float* ws  = (float*)d_ws;

    // zero barriers + accumulators + S1/S2/SG sums: floats [0, 9216), every call.
    hipMemsetAsync(ws, 0, 9216 * sizeof(float), stream);
    k_fused<<<GRIDN, NTHR, 0, stream>>>(z, g, ws, out);
}

// Round 16
// 82.098 us; speedup vs baseline: 6.5990x; 4.1043x over previous
//
#include <hip/hip_runtime.h>
#include <hip/hip_bf16.h>
#include <math.h>

#define NS (16*256*64)   // 262144 samples
#define NCHUNK (NS/64)   // 4096
#define D 32
#define K 8

typedef __attribute__((ext_vector_type(8))) short bf16x8;
typedef __attribute__((ext_vector_type(8))) float f32x8;
typedef __attribute__((ext_vector_type(8))) __bf16 bf16v8;
typedef __attribute__((ext_vector_type(16))) float f32x16;

// ws float layout ([0,64) zeroed by k_moments block 0 each call)
#define WS_ENERGY   0
#define WS_COVDIAG  1
#define WS_DONE     2      // k_energy finalize counter
#define WS_DONE2    3      // k_redprep last-block counter
#define WS_C        16
#define WS_COEF     24
#define WS_SG       32
#define WS_S1       64
#define WS_S2       1024
#define WS_FRAGA    9216   // 16 frags x 64 lanes x 16B
#define WS_FRAGB    13312  // 2 frags x 64 lanes x 16B (rows>=8 unused by E: safe un-zeroed)
#define WS_PART     16384
#define PART_STRIDE 8456

__device__ __forceinline__ bf16x8 cvt8(f32x8 v) {
    union { bf16v8 h; bf16x8 s; } u;
    u.h = __builtin_convertvector(v, bf16v8);
    return u.s;
}
__device__ __forceinline__ unsigned short f2bf1(float f) {
    union { __bf16 h; unsigned short s; } u;
    u.h = (__bf16)f;
    return u.s;
}
__device__ __forceinline__ float bf2f(unsigned short u) {
    union { unsigned u32; float f; } v;
    v.u32 = ((unsigned)u) << 16;
    return v.f;
}
__device__ __forceinline__ float rdlane(float v, int lane) {
    return __uint_as_float(__builtin_amdgcn_readlane(__float_as_uint(v), lane));
}

// ---------------- K1: moments (R10/R12-proven body). Block 0 zeroes ctrl region.
__global__ __launch_bounds__(256) void k_moments(const float* __restrict__ z,
                                                 const float* __restrict__ g,
                                                 float* __restrict__ ws) {
    __shared__ __align__(16) unsigned short zbt[32][72];  // bf16 z^T, pad 72
    __shared__ __align__(16) unsigned short gbt[8][72];   // bf16 gamma^T
    const int t   = threadIdx.x;
    const int bid = blockIdx.x;
    const int w   = t >> 6;
    const int l   = t & 63;
    const int col = l & 31;
    const int nh  = l >> 5;
    const int k0  = 2 * w;
    const int sz  = t >> 2;        // staged sample
    const int dq  = (t & 3) * 8;   // staged dim octet

    if (bid == 0 && t < 64) ws[t] = 0.0f;   // counters/accumulators (visible to K2 at launch boundary)

    f32x16 acc0 = {}, acc1 = {};
    float s1a = 0.f, s1b = 0.f;
    float sg8[8];
#pragma unroll
    for (int k = 0; k < 8; k++) sg8[k] = 0.0f;

    int c = bid;
    float4 za, zb4, ga4, gb4;
    {
        const float* zp = z + ((size_t)(c * 64 + sz)) * 32 + dq;
        za  = *(const float4*)zp;
        zb4 = *(const float4*)(zp + 4);
        if (t < 64) {
            const float* gp = g + ((size_t)(c * 64 + t)) * 8;
            ga4 = *(const float4*)gp;
            gb4 = *(const float4*)(gp + 4);
        }
    }
    for (; c < NCHUNK; c += gridDim.x) {
        __syncthreads();
        {
            float zf8[8] = {za.x, za.y, za.z, za.w, zb4.x, zb4.y, zb4.z, zb4.w};
#pragma unroll
            for (int i = 0; i < 8; i++) {
                int d = dq + i;
                zbt[d][sz ^ (((d >> 3) & 3) << 3)] = f2bf1(zf8[i]);
            }
            if (t < 64) {
                float gf8[8] = {ga4.x, ga4.y, ga4.z, ga4.w, gb4.x, gb4.y, gb4.z, gb4.w};
#pragma unroll
                for (int k = 0; k < 8; k++) {
                    gbt[k][t] = f2bf1(gf8[k]);
                    sg8[k] += gf8[k];            // exact f32 SG in staging-thread regs
                }
            }
        }
        {
            int cn = c + gridDim.x;
            if (cn < NCHUNK) {
                const float* zp = z + ((size_t)(cn * 64 + sz)) * 32 + dq;
                za  = *(const float4*)zp;
                zb4 = *(const float4*)(zp + 4);
                if (t < 64) {
                    const float* gp = g + ((size_t)(cn * 64 + t)) * 8;
                    ga4 = *(const float4*)gp;
                    gb4 = *(const float4*)(gp + 4);
                }
            }
        }
        __syncthreads();
        const int xs = ((col >> 3) & 3) << 3;
#pragma unroll
        for (int sc = 0; sc < 4; sc++) {
            const int s0 = sc * 16 + nh * 8;
            bf16x8 af = *(const bf16x8*)&zbt[col][s0 ^ xs];
            bf16x8 g0 = *(const bf16x8*)&gbt[k0][s0];
            bf16x8 g1 = *(const bf16x8*)&gbt[k0 + 1][s0];
            f32x8 p0, p1;
#pragma unroll
            for (int j = 0; j < 8; j++) {
                float zf = bf2f((unsigned short)af[j]);
                p0[j] = bf2f((unsigned short)g0[j]) * zf;
                p1[j] = bf2f((unsigned short)g1[j]) * zf;
                s1a += p0[j];  s1b += p1[j];
            }
            acc0 = __builtin_amdgcn_mfma_f32_32x32x16_bf16(af, cvt8(p0), acc0, 0, 0, 0);
            acc1 = __builtin_amdgcn_mfma_f32_32x32x16_bf16(af, cvt8(p1), acc1, 0, 0, 0);
        }
    }
    s1a += __shfl_xor(s1a, 32);  s1b += __shfl_xor(s1b, 32);

    float* pb = ws + WS_PART + (size_t)bid * PART_STRIDE;
#pragma unroll
    for (int r = 0; r < 16; r++) {
        int row = (r & 3) + 8 * (r >> 2) + 4 * nh;   // HW-verified C/D map (m74/m101)
        pb[(size_t)k0 * 1024 + row * 32 + col]       = acc0[r];
        pb[(size_t)(k0 + 1) * 1024 + row * 32 + col] = acc1[r];
    }
    if (l < 32) {
        pb[8192 + k0 * 32 + col]       = s1a;
        pb[8192 + (k0 + 1) * 32 + col] = s1b;
    }
    if (t < 64) {   // SG: staging wave holds partials
#pragma unroll
        for (int k = 0; k < 8; k++) {
            float v = sg8[k];
#pragma unroll
            for (int m = 1; m < 64; m <<= 1) v += __shfl_xor(v, m);
            if (t == 0) pb[8448 + k] = v;
        }
    }
}

// ---------------- K2: tree-reduce partials (R8-proven) + last block runs all 8
// Gauss-Jordans (one wave per matrix) via done-counter -- no spin barrier.
__global__ __launch_bounds__(1024) void k_redprep(float* __restrict__ ws, int nblk) {
    __shared__ float red[16][64];
    __shared__ float Am8[8][32][33];
    __shared__ float mus8[8][32];
    __shared__ float bLs8[8][32];
    __shared__ unsigned lastflag;

    const int t  = threadIdx.x;
    const int el = t & 63;
    const int bg = t >> 6;
    const int e  = blockIdx.x * 64 + el;
    const float* part = ws + WS_PART;
    float s = 0.0f;
    if (e < PART_STRIDE) {
        for (int b = bg; b < nblk; b += 16)
            s += part[(size_t)b * PART_STRIDE + e];
    }
    red[bg][el] = s;
    __syncthreads();
#pragma unroll
    for (int h = 8; h > 0; h >>= 1) {
        if (bg < h) red[bg][el] += red[bg + h][el];
        __syncthreads();
    }
    if (bg == 0 && e < PART_STRIDE) {
        float v = red[0][el];
        if (e < 8192)       ws[WS_S2 + e] = v;
        else if (e < 8448)  ws[WS_S1 + (e - 8192)] = v;
        else                ws[WS_SG + (e - 8448)] = v;
    }
    // ---- done-counter: last block continues into prep ----
    __syncthreads();
    if (t == 0) {
        __threadfence();   // cache-wide L2 writeback: this block's S-stores reach coherent point
        unsigned old = atomicAdd((unsigned*)ws + WS_DONE2, 1u);
        lastflag = (old == gridDim.x - 1) ? 1u : 0u;
    }
    __syncthreads();
    if (!lastflag) return;

    // ---- PREP: 8 waves, wave w8 = matrix w8 (readlane GJ, wave-local) ----
    const int w8  = t >> 6;
    const int l   = t & 63;
    const int c32 = l & 31;
    const bool pa    = (w8 < 8);
    const bool right = pa && (l >= 32);

    float sgk = 1.0f;
    if (pa) sgk = ws[WS_SG + w8];
    if (pa && l < 32) mus8[w8][l] = ws[WS_S1 + w8 * 32 + l] / sgk;
    __syncthreads();

    float logdet = 0.0f;
    if (pa) {
        const float mc  = mus8[w8][c32];
        const float rsg = 1.0f / sgk;
        float x[32];
        float dval = 1.0f;
#pragma unroll
        for (int r = 0; r < 32; r++) {
            float v;
            if (right) {
                v = (r == c32) ? 1.0f : 0.0f;
            } else {
                v = ws[WS_S2 + w8 * 1024 + r * 32 + c32] * rsg - mus8[w8][r] * mc;
                if (r == c32) { v += 1.0e-6f + 1.0e-9f; dval = v; }
            }
            x[r] = v;
        }
        {
            float tdi = right ? 0.0f : 1.0f / dval;
#pragma unroll
            for (int m = 1; m < 64; m <<= 1) tdi += __shfl_xor(tdi, m);
            if (l == 0) atomicAdd(&ws[WS_COVDIAG], tdi);
        }
#pragma unroll
        for (int j = 0; j < 32; j++) {
            float piv = rdlane(x[j], j);
            float rp  = 1.0f / piv;
            logdet += __logf(piv);
            x[j] *= rp;
#pragma unroll
            for (int r = 0; r < 32; r++) {
                if (r == j) continue;
                float m = rdlane(x[r], j);
                x[r] -= m * x[j];
            }
        }
        if (right) {
#pragma unroll
            for (int r = 0; r < 32; r++) Am8[w8][r][c32] = x[r];
        }
        if (l == 0) {
            float phi = sgk / (float)NS;
            ws[WS_COEF + w8] = phi * __expf(-(8.0f * 1.8378770664093453f + 0.25f * logdet));
        }
    }
    __syncthreads();
    if (pa && l < 32) {
        float s2 = 0.0f;
#pragma unroll
        for (int c = 0; c < 32; c++) s2 += Am8[w8][c32][c] * mus8[w8][c];
        bLs8[w8][c32] = s2;
    }
    __syncthreads();
    if (pa) {
        float cm = (l < 32) ? mus8[w8][c32] * bLs8[w8][c32] : 0.0f;
#pragma unroll
        for (int m = 1; m < 64; m <<= 1) cm += __shfl_xor(cm, m);
        if (l == 0) ws[WS_C + w8] = cm;

        const int ph = l >> 5;
#pragma unroll
        for (int h = 0; h < 2; h++) {
            int cb = ph * 8 + 16 * h;
            unsigned uu[4];
#pragma unroll
            for (int q = 0; q < 4; q++) {
                unsigned lo2 = f2bf1(Am8[w8][c32][cb + 2 * q]);
                unsigned hi2 = f2bf1(Am8[w8][c32][cb + 2 * q + 1]);
                uu[q] = lo2 | (hi2 << 16);
            }
            ((uint4*)(ws + WS_FRAGA))[(w8 * 2 + h) * 64 + l] = make_uint4(uu[0], uu[1], uu[2], uu[3]);
        }
        if (c32 == w8) {
#pragma unroll
            for (int h = 0; h < 2; h++) {
                int cb = ph * 8 + 16 * h;
                unsigned uu[4];
#pragma unroll
                for (int q = 0; q < 4; q++) {
                    unsigned lo2 = f2bf1(bLs8[w8][cb + 2 * q]);
                    unsigned hi2 = f2bf1(bLs8[w8][cb + 2 * q + 1]);
                    uu[q] = lo2 | (hi2 << 16);
                }
                ((uint4*)(ws + WS_FRAGB))[h * 64 + l] = make_uint4(uu[0], uu[1], uu[2], uu[3]);
            }
        }
    }
}

// ---------------- K3: energy (R12-proven body); last block finalizes out.
__global__ __launch_bounds__(512) void k_energy(const float* __restrict__ z,
                                                float* __restrict__ ws,
                                                float* __restrict__ out) {
    __shared__ float redw[8];
    const int t   = threadIdx.x;
    const int w   = t >> 6;
    const int l   = t & 63;
    const int col = l & 31;
    const int nh  = l >> 5;

    const uint4* fragA = (const uint4*)(ws + WS_FRAGA);
    const uint4* fragB = (const uint4*)(ws + WS_FRAGB);
    float cf[8], cc[8];
#pragma unroll
    for (int k = 0; k < 8; k++) { cf[k] = ws[WS_COEF + k]; cc[k] = ws[WS_C + k]; }
    uint4 fbu0 = fragB[l];
    uint4 fbu1 = fragB[64 + l];

    float En = 0.0f;
    for (int ci = 0; ci < 2; ci++) {
        const int chunk = (blockIdx.x * 8 + w) * 2 + ci;
        const int n0 = chunk * 32;
        const float* zb = z + (size_t)(n0 + col) * 32 + nh * 8;
        float4 a0 = *(const float4*)(zb + 0);
        float4 a1 = *(const float4*)(zb + 4);
        float4 a2 = *(const float4*)(zb + 16);
        float4 a3 = *(const float4*)(zb + 20);
        f32x8 zlo = {a0.x,a0.y,a0.z,a0.w,a1.x,a1.y,a1.z,a1.w};
        f32x8 zhi = {a2.x,a2.y,a2.z,a2.w,a3.x,a3.y,a3.z,a3.w};
        bf16x8 b0 = cvt8(zlo), b1 = cvt8(zhi);
        float olo[4], ohi[4];
#pragma unroll
        for (int j = 0; j < 4; j++) {
            float mlo = nh ? zlo[j] : zlo[j + 4];
            float mhi = nh ? zhi[j] : zhi[j + 4];
            olo[j] = __shfl_xor(mlo, 32);
            ohi[j] = __shfl_xor(mhi, 32);
        }
        float zdot[16];
#pragma unroll
        for (int j = 0; j < 4; j++) {
            zdot[j]      = nh ? olo[j]     : zlo[j];
            zdot[4 + j]  = nh ? zlo[4 + j] : olo[j];
            zdot[8 + j]  = nh ? ohi[j]     : zhi[j];
            zdot[12 + j] = nh ? zhi[4 + j] : ohi[j];
        }
        f32x16 acc2 = {};
        acc2 = __builtin_amdgcn_mfma_f32_32x32x16_bf16(*(const bf16x8*)&fbu0, b0, acc2, 0, 0, 0);
        acc2 = __builtin_amdgcn_mfma_f32_32x32x16_bf16(*(const bf16x8*)&fbu1, b1, acc2, 0, 0, 0);
        float oth[4];
#pragma unroll
        for (int r = 0; r < 4; r++) oth[r] = __shfl_xor(acc2[r], 32);
        float pk[8];
#pragma unroll
        for (int k = 0; k < 8; k++) {
            uint4 fa0u = fragA[(k * 2 + 0) * 64 + l];
            uint4 fa1u = fragA[(k * 2 + 1) * 64 + l];
            f32x16 acc = {};
            acc = __builtin_amdgcn_mfma_f32_32x32x16_bf16(*(const bf16x8*)&fa0u, b0, acc, 0, 0, 0);
            acc = __builtin_amdgcn_mfma_f32_32x32x16_bf16(*(const bf16x8*)&fa1u, b1, acc, 0, 0, 0);
            float p = 0.0f;
#pragma unroll
            for (int r = 0; r < 16; r++) p += acc[r] * zdot[r];
            p += __shfl_xor(p, 32);
            pk[k] = p;
        }
        float ssum = 0.0f;
#pragma unroll
        for (int k = 0; k < 8; k++) {
            float d2 = (k < 4) ? (nh ? oth[k] : acc2[k]) : (nh ? acc2[k - 4] : oth[k - 4]);
            float E = pk[k] - 2.0f * d2 + cc[k];
            ssum += cf[k] * __expf(-0.5f * E);
        }
        En += -__logf(ssum + 1.0e-6f);
    }
#pragma unroll
    for (int m = 1; m < 64; m <<= 1) En += __shfl_xor(En, m);
    if (l == 0) redw[w] = En;
    __syncthreads();
    if (t == 0) {
        float s = 0.0f;
#pragma unroll
        for (int i = 0; i < 8; i++) s += redw[i];
        atomicAdd(&ws[WS_ENERGY], s);
        __threadfence();
        unsigned old = atomicAdd((unsigned*)ws + WS_DONE, 1u);
        if (old == gridDim.x - 1) {
            float se = atomicAdd(&ws[WS_ENERGY], 0.0f);   // coherent RMW read
            se = se * 0.5f / (float)NS;   // each sample counted by 2 lane-halves
            if (!isfinite(se)) se = 0.0f;
            float cd = ws[WS_COVDIAG];
            if (!isfinite(cd)) cd = 0.0f;
            out[0] = 0.1f * se + 0.005f * cd;
        }
    }
}

extern "C" void kernel_launch(void* const* d_in, const int* in_sizes, int n_in,
                              void* d_out, int out_size, void* d_ws, size_t ws_size,
                              hipStream_t stream) {
    const float* z = (const float*)d_in[0];
    const float* g = (const float*)d_in[1];
    float* out = (float*)d_out;
    float* ws  = (float*)d_ws;

    long avail = (long)(ws_size / 4) - WS_PART;
    int nblk = (int)(avail / PART_STRIDE);
    if (nblk > 512) nblk = 512;
    if (nblk < 1)   nblk = 1;

    k_moments<<<nblk, 256, 0, stream>>>(z, g, ws);
    k_redprep<<<(PART_STRIDE + 63) / 64, 1024, 0, stream>>>(ws, nblk);
    k_energy<<<512, 512, 0, stream>>>(z, ws, out);
}